// Round 23
// baseline (340.481 us; speedup 1.0000x reference)
//
#include <hip/hip_runtime.h>
#include <hip/hip_bf16.h>

typedef __attribute__((ext_vector_type(8))) short bf16x8;
typedef __attribute__((ext_vector_type(4))) float f32x4;

constexpr int NB = 16, CIN = 256, COUT = 256, TDIM = 4096, KS = 3, PADV = 1;
constexpr int TT = 64;             // t per block
constexpr int NSTEP = 12;          // 4 c-blocks x 3 taps

typedef __attribute__((address_space(1))) const unsigned int gu32;
typedef __attribute__((address_space(3))) unsigned int lu32;

static __device__ __forceinline__ ushort f2bf(float f) {
    union { __hip_bfloat16 h; ushort u; } cv;
    cv.h = __float2bfloat16(f);
    return cv.u;
}

// interp: r[i] = bf16( wa * a0[i] + wb * a1[i] )  — R19-measured dot2 form.
static __device__ __forceinline__ bf16x8 interp8(bf16x8 a0, bf16x8 a1,
                                                 unsigned int wpk, float wa, float wb) {
    union { bf16x8 v; unsigned int u[4]; } A0, A1;
    A0.v = a0; A1.v = a1;
    bf16x8 r;
#if __has_builtin(__builtin_amdgcn_fdot2_f32_bf16) && __has_builtin(__builtin_amdgcn_perm)
    typedef __attribute__((ext_vector_type(2))) __bf16 bf16x2v;
    bf16x2v w2 = __builtin_bit_cast(bf16x2v, wpk);
    #pragma unroll
    for (int j = 0; j < 4; ++j) {
        unsigned int pe = __builtin_amdgcn_perm(A1.u[j], A0.u[j], 0x05040100u); // elem 2j
        unsigned int po = __builtin_amdgcn_perm(A1.u[j], A0.u[j], 0x07060302u); // elem 2j+1
        float ve = __builtin_amdgcn_fdot2_f32_bf16(__builtin_bit_cast(bf16x2v, pe), w2, 0.0f, false);
        float vo = __builtin_amdgcn_fdot2_f32_bf16(__builtin_bit_cast(bf16x2v, po), w2, 0.0f, false);
        r[2 * j]     = (short)f2bf(ve);
        r[2 * j + 1] = (short)f2bf(vo);
    }
#else
    #pragma unroll
    for (int j = 0; j < 4; ++j) {
        float a0l = __uint_as_float(A0.u[j] << 16);
        float a0h = __uint_as_float(A0.u[j] & 0xffff0000u);
        float a1l = __uint_as_float(A1.u[j] << 16);
        float a1h = __uint_as_float(A1.u[j] & 0xffff0000u);
        r[2 * j]     = (short)f2bf(a0l * wa + a1l * wb);
        r[2 * j + 1] = (short)f2bf(a0h * wa + a1h * wb);
    }
#endif
    return r;
}

// x (B,C,T) f32 -> xT (B,T,C) bf16 (64c x 64t LDS tile), PLUS fused prepack of
// wp2 (reg-frag W pack): 4096 blocks x 48 items = 196608.
// wp2 slot = (((s*2+ot)*4+wid)*2+kb)*2+mf, 1 KB each; o = ot*128+wid*32+mf*16+
// (lane&15), c = (s/3)*64 + kb*32 + (lane>>4)*8 + e, k = s%3.
__global__ __launch_bounds__(256) void transpose_prepack(
    const float* __restrict__ x, ushort* __restrict__ xT,
    const float* __restrict__ w, __hip_bfloat16* __restrict__ wp2) {
    __shared__ ushort tile[64][72];
    const int b  = blockIdx.z;
    const int c0 = blockIdx.y * 64;
    const int t0 = blockIdx.x * 64;
    const int tid = threadIdx.x;
    // fused prepack: 48 items per block
    {
        int gid = ((blockIdx.z * gridDim.y + blockIdx.y) * gridDim.x + blockIdx.x);
        if (tid < 48) {
            int idx = gid * 48 + tid;                  // < 196608
            int e    = idx & 7;
            int lane = (idx >> 3) & 63;
            int mf   = (idx >> 9) & 1;
            int kb   = (idx >> 10) & 1;
            int wid  = (idx >> 11) & 3;
            int ot   = (idx >> 13) & 1;
            int s    = idx >> 14;                      // 0..11
            int o = ot * 128 + wid * 32 + mf * 16 + (lane & 15);
            int k = s % 3;
            int c = (s / 3) * 64 + kb * 32 + (lane >> 4) * 8 + e;
            wp2[idx] = __float2bfloat16(w[(o * CIN + c) * KS + k]);
        }
    }
    {
        const int c  = tid >> 2;
        const int tq = (tid & 3) << 4;
        const float* src = x + ((size_t)(b * CIN + c0 + c)) * TDIM + t0 + tq;
        #pragma unroll
        for (int i = 0; i < 4; ++i) {
            float4 f = *(const float4*)(src + 4 * i);
            tile[tq + 4 * i + 0][c] = f2bf(f.x);
            tile[tq + 4 * i + 1][c] = f2bf(f.y);
            tile[tq + 4 * i + 2][c] = f2bf(f.z);
            tile[tq + 4 * i + 3][c] = f2bf(f.w);
        }
    }
    __syncthreads();
    {
        const int t = tid >> 2;
        const int q = tid & 3;
        const uint4* lp = (const uint4*)&tile[t][q * 16];
        uint4 v0 = lp[0], v1 = lp[1];
        uint4* dst = (uint4*)(xT + ((size_t)b * TDIM + t0 + t) * CIN + c0 + q * 16);
        dst[0] = v0;
        dst[1] = v1;
    }
}

// legacy pack for the fallback kernel (LDS image, pre-swizzled)
__global__ __launch_bounds__(256) void prepack_w(const float* __restrict__ w,
                                                 __hip_bfloat16* __restrict__ wp) {
    int idx = blockIdx.x * 256 + threadIdx.x;
    if (idx >= NSTEP * COUT * 64) return;
    int e  = idx & 7;
    int j  = (idx >> 3) & 7;
    int o  = (idx >> 6) & (COUT - 1);
    int s  = idx >> 14;
    int k  = s % 3;
    int c  = (s / 3) * 64 + ((j ^ (o & 7)) << 3) + e;
    wp[idx] = __float2bfloat16(w[(o * CIN + c) * KS + k]);
}

// ---- main kernel: 512 threads, 256o x 64t tile, shared V (no ot duplication) ----
__global__ __launch_bounds__(512, 8) void deform_mfma_xt(
    const ushort* __restrict__ xT,            // (NB, TDIM, CIN) bf16
    const float* __restrict__ off,            // (NB, 2*KS, TDIM, 1)
    const ushort* __restrict__ wp2,           // reg-frag pack, 384 KB
    const float* __restrict__ bias,           // (COUT)
    float* __restrict__ out)                  // (NB, COUT, TDIM)
{
    __shared__ ushort v_s[TT * 64];         // 8 KB swizzled V tile [t][c]
    __shared__ int4   sP[KS][TT];           // {base*CIN, wpk, waf32, wbf32}

    const int tid = threadIdx.x;

    // XCD swizzle: 1024 blocks; XCD q (= bid&7) owns batches {2q, 2q+1}.
    const int bid = blockIdx.x;            // 0..1023
    const int q   = bid & 7;
    const int r   = bid >> 3;              // 0..127
    const int b   = 2 * q + (r >> 6);
    const int tt0 = (r & 63) * TT;

    // ---- Phase A: per-(k,t) base row + pair-ordered weights ----
    if (tid < KS * TT) {
        int k = tid >> 6, j = tid & (TT - 1);
        int t = tt0 + j;
        float dyr = off[((b * 2 * KS + 2 * k) * TDIM) + t];
        float dxr = off[((b * 2 * KS + 2 * k + 1) * TDIM) + t];
        float dyk = dyr - (float)(k - PADV);
        float py  = (float)(t - PADV + k) + dyk;
        float i0f = floorf(py);
        float fr  = py - i0f;
        int i0 = (int)i0f, i1 = i0 + 1;
        float wx = fmaxf(0.0f, 1.0f - fabsf(dxr));
        float w0 = (1.0f - fr) * wx * ((i0 >= 0 && i0 < TDIM) ? 1.0f : 0.0f);
        float w1 = fr * wx * ((i1 >= 0 && i1 < TDIM) ? 1.0f : 0.0f);
        int base = min(max(i0, 0), TDIM - 2);
        bool iA = (i0 == base);
        float wa = iA ? w0 : ((i0 + 1 == base) ? w1 : 0.0f);
        float wb = iA ? w1 : ((i0 == base + 1) ? w0 : 0.0f);
        int4 p;
        p.x = base * CIN;                  // pre-scaled row offset (elements)
        p.y = (int)((unsigned)f2bf(wa) | ((unsigned)f2bf(wb) << 16));
        p.z = __float_as_int(wa);
        p.w = __float_as_int(wb);
        sP[k][j] = p;
    }

    const int wid  = tid >> 6;             // 0..7 -> o sub-tile (wid*32)
    const int lane = tid & 63;
    const int lr   = lane & 15;
    const int lg   = lane >> 4;
    const int ot   = wid >> 2;             // wp2 pack dims
    const int wid3 = wid & 3;

    // V-phase mapping: 8 lanes per t, 64 t-rows over 512 threads (1 row/thread)
    const int tg   = tid >> 3;             // 0..63
    const int slot = tid & 7;
    const int voffA = (tg * 128 + slot * 16) ^ ((tg & 7) << 4);

    f32x4 acc[2][4];
    #pragma unroll
    for (int i = 0; i < 2; ++i)
        #pragma unroll
        for (int j = 0; j < 4; ++j) acc[i][j] = (f32x4)0.0f;

    const ushort* xTb = xT + (size_t)b * TDIM * CIN;

    __syncthreads();   // sP visible to all

    // ---- Prologue: W(0) frags + gather(0) + interp -> pk ----
    bf16x8 af0, af1, af2, af3;
    bf16x8 pk0;
    {
        const ushort* wslot = wp2 + (size_t)(((0 * 2 + ot) * 4 + wid3) * 4) * 512 + lane * 8;
        af0 = *(const bf16x8*)(wslot);
        af1 = *(const bf16x8*)(wslot + 512);
        af2 = *(const bf16x8*)(wslot + 1024);
        af3 = *(const bf16x8*)(wslot + 1536);
        int4 e0 = sP[0][tg];
        const ushort* rowA = xTb + e0.x + slot * 8;
        bf16x8 a0 = *(const bf16x8*)rowA;
        bf16x8 a1 = *(const bf16x8*)(rowA + CIN);
        pk0 = interp8(a0, a1, (unsigned)e0.y, __int_as_float(e0.z), __int_as_float(e0.w));
    }

    #pragma unroll 1
    for (int s = 0; s < NSTEP; ++s) {
        const int sn  = (s + 1 < NSTEP) ? s + 1 : NSTEP - 1;   // clamped prefetch
        const int kn  = sn % 3;
        const int cbn = (sn / 3) * 64;

        __builtin_amdgcn_s_barrier();          // B1: v_s writable (MFMA(s-1) done)
        __builtin_amdgcn_sched_barrier(0);

        // commit V(s) from regs
        *(bf16x8*)((char*)v_s + voffA) = pk0;

        // prefetch W(s+1) frags -> an*
        const ushort* wslot = wp2 + (size_t)(((sn * 2 + ot) * 4 + wid3) * 4) * 512 + lane * 8;
        bf16x8 an0 = *(const bf16x8*)(wslot);
        bf16x8 an1 = *(const bf16x8*)(wslot + 512);
        bf16x8 an2 = *(const bf16x8*)(wslot + 1024);
        bf16x8 an3 = *(const bf16x8*)(wslot + 1536);

        // prefetch gather(s+1) -> ga* (stays in flight through MFMA)
        int4 e0 = sP[kn][tg];
        const ushort* rowA = xTb + e0.x + cbn + slot * 8;
        bf16x8 ga0 = *(const bf16x8*)rowA;
        bf16x8 ga1 = *(const bf16x8*)(rowA + CIN);

        __builtin_amdgcn_sched_barrier(0);
        // own ds_write (and sP reads) complete; vmcnt NOT drained
        asm volatile("s_waitcnt lgkmcnt(0)" ::: "memory");
        __builtin_amdgcn_sched_barrier(0);
        __builtin_amdgcn_s_barrier();          // B2: v_s ready for all waves
        __builtin_amdgcn_sched_barrier(0);

        // ---- MFMA(s): wave computes 32(o) x 64(t), K=64; af already in regs ----
        #pragma unroll
        for (int kb = 0; kb < 2; ++kb) {
            const int kk = kb * 32 + lg * 8;
            bf16x8 bfr[4];
            #pragma unroll
            for (int nf = 0; nf < 4; ++nf) {
                int tc = nf * 16 + lr;
                int byte = (tc * 128 + kk * 2) ^ ((tc & 7) << 4);
                bfr[nf] = *(const bf16x8*)((const char*)v_s + byte);
            }
            bf16x8 a0 = kb ? af2 : af0;
            bf16x8 a1 = kb ? af3 : af1;
            #pragma unroll
            for (int nf = 0; nf < 4; ++nf) {
                acc[0][nf] = __builtin_amdgcn_mfma_f32_16x16x32_bf16(a0, bfr[nf], acc[0][nf], 0, 0, 0);
                acc[1][nf] = __builtin_amdgcn_mfma_f32_16x16x32_bf16(a1, bfr[nf], acc[1][nf], 0, 0, 0);
            }
        }
        __builtin_amdgcn_sched_barrier(0);

        // ---- interp(s+1): compiler inserts vmcnt waits for ga* here ----
        pk0 = interp8(ga0, ga1, (unsigned)e0.y, __int_as_float(e0.z), __int_as_float(e0.w));
        af0 = an0; af1 = an1; af2 = an2; af3 = an3;
    }

    // ---- Epilogue: D col = lane&15 (t), row = (lane>>4)*4 + reg (o) ----
    #pragma unroll
    for (int mf = 0; mf < 2; ++mf) {
        #pragma unroll
        for (int rg = 0; rg < 4; ++rg) {
            int o = wid * 32 + mf * 16 + lg * 4 + rg;
            float bv = bias[o];
            float* orow = out + (size_t)(b * COUT + o) * TDIM + tt0;
            #pragma unroll
            for (int nf = 0; nf < 4; ++nf)
                __builtin_nontemporal_store(acc[mf][nf][rg] + bv, &orow[nf * 16 + lr]);
        }
    }
}

// ---- fallback (proven R6 kernel, 128-t tile): scalar gathers from x ----
__global__ __launch_bounds__(512, 4) void deform_mfma_gather(
    const float* __restrict__ x,
    const float* __restrict__ off,
    const __hip_bfloat16* __restrict__ wp,
    const float* __restrict__ bias,
    float* __restrict__ out)
{
    __shared__ ushort w_s[COUT * 64];
    __shared__ ushort v_s[128 * 64];
    __shared__ int4   sP[KS][128];

    const int tid = threadIdx.x;
    const int bid  = blockIdx.x;
    const int q    = bid & 7;
    const int r    = bid >> 3;
    const int b    = 2 * q + (r >> 5);
    const int tt0  = (r & 31) * 128;

    if (tid < KS * 128) {
        int k = tid >> 7, j = tid & 127;
        int t = tt0 + j;
        float dyr = off[((b * 2 * KS + 2 * k) * TDIM) + t];
        float dxr = off[((b * 2 * KS + 2 * k + 1) * TDIM) + t];
        float py  = (float)(t - PADV + k) + dyr - (float)(k - PADV);
        float i0f = floorf(py);
        float fr  = py - i0f;
        int i0 = (int)i0f, i1 = i0 + 1;
        float wx = fmaxf(0.0f, 1.0f - fabsf(dxr));
        float w0 = (1.0f - fr) * wx * ((i0 >= 0 && i0 < TDIM) ? 1.0f : 0.0f);
        float w1 = fr * wx * ((i1 >= 0 && i1 < TDIM) ? 1.0f : 0.0f);
        int4 p;
        p.x = min(max(i0, 0), TDIM - 1);
        p.y = min(max(i1, 0), TDIM - 1);
        p.z = __float_as_int(w0);
        p.w = __float_as_int(w1);
        sP[k][j] = p;
    }

    const int wid    = tid >> 6;
    const int lane   = tid & 63;
    const int o_base = (wid >> 1) * 64;
    const int t_base = (wid & 1) * 64;
    const int lr     = lane & 15;
    const int lg     = lane >> 4;

    f32x4 acc[4][4];
    #pragma unroll
    for (int i = 0; i < 4; ++i)
        #pragma unroll
        for (int j = 0; j < 4; ++j) acc[i][j] = (f32x4)0.0f;

    const float* xb = x + (size_t)b * CIN * TDIM;

    for (int cb = 0; cb < 4; ++cb) {
      for (int k = 0; k < 3; ++k) {
        const int s_idx = cb * 3 + k;
        const int c0    = cb * 64;
        __syncthreads();
        {
            const char* gbase = (const char*)wp + (size_t)s_idx * 32768 + wid * 4096 + lane * 16;
            char* lbase = (char*)w_s + wid * 4096;
            #pragma unroll
            for (int i = 0; i < 4; ++i)
                __builtin_amdgcn_global_load_lds((gu32*)(gbase + i * 1024),
                                                 (lu32*)(lbase + i * 1024), 16, 0, 0);
        }
        {
            const int coct0 = tid >> 7;
            const int t     = tid & 127;
            int4 p = sP[k][t];
            const float* xr0 = xb + (size_t)(c0 + coct0 * 8) * TDIM;
            const float* xr1 = xr0 + (size_t)32 * TDIM;
            float g0[16], g1[16];
            #pragma unroll
            for (int i = 0; i < 8; ++i) {
                g0[2 * i]     = xr0[p.x];
                g0[2 * i + 1] = xr0[p.y];
                xr0 += TDIM;
            }
            #pragma unroll
            for (int i = 0; i < 8; ++i) {
                g1[2 * i]     = xr1[p.x];
                g1[2 * i + 1] = xr1[p.y];
                xr1 += TDIM;
            }
            float w0 = __int_as_float(p.z), w1 = __int_as_float(p.w);
            bf16x8 pk0, pk1;
            #pragma unroll
            for (int i = 0; i < 8; ++i) {
                pk0[i] = (short)f2bf(g0[2 * i] * w0 + g0[2 * i + 1] * w1);
                pk1[i] = (short)f2bf(g1[2 * i] * w0 + g1[2 * i + 1] * w1);
            }
            int row = t * 128;
            int swz = (t & 7) << 4;
            *(bf16x8*)((char*)v_s + ((row + coct0 * 16) ^ swz))       = pk0;
            *(bf16x8*)((char*)v_s + ((row + (coct0 + 4) * 16) ^ swz)) = pk1;
        }
        __syncthreads();
        #pragma unroll
        for (int kb = 0; kb < 2; ++kb) {
            const int kk = kb * 32 + lg * 8;
            bf16x8 bfr[4];
            #pragma unroll
            for (int nf = 0; nf < 4; ++nf) {
                int tc = t_base + nf * 16 + lr;
                int byte = (tc * 128 + kk * 2) ^ ((tc & 7) << 4);
                bfr[nf] = *(const bf16x8*)((const char*)v_s + byte);
            }
            #pragma unroll
            for (int mf = 0; mf < 4; ++mf) {
                int o  = o_base + mf * 16 + lr;
                int byte = (o * 128 + kk * 2) ^ ((o & 7) << 4);
                bf16x8 af = *(const bf16x8*)((const char*)w_s + byte);
                #pragma unroll
                for (int nf = 0; nf < 4; ++nf)
                    acc[mf][nf] = __builtin_amdgcn_mfma_f32_16x16x32_bf16(
                        af, bfr[nf], acc[mf][nf], 0, 0, 0);
            }
        }
      }
    }

    #pragma unroll
    for (int mf = 0; mf < 4; ++mf) {
        #pragma unroll
        for (int rg = 0; rg < 4; ++rg) {
            int o = o_base + mf * 16 + lg * 4 + rg;
            float bv = bias[o];
            float* orow = out + (size_t)(b * COUT + o) * TDIM + tt0 + t_base;
            #pragma unroll
            for (int nf = 0; nf < 4; ++nf)
                orow[nf * 16 + lr] = acc[mf][nf][rg] + bv;
        }
    }
}

extern "C" void kernel_launch(void* const* d_in, const int* in_sizes, int n_in,
                              void* d_out, int out_size, void* d_ws, size_t ws_size,
                              hipStream_t stream) {
    const float* x    = (const float*)d_in[0];
    const float* off  = (const float*)d_in[1];
    const float* w    = (const float*)d_in[2];
    const float* bias = (const float*)d_in[3];
    float* out = (float*)d_out;

    const size_t xt_off  = 512 * 1024;
    const size_t xt_need = xt_off + (size_t)NB * TDIM * CIN * sizeof(ushort);

    if (ws_size >= xt_need) {
        ushort* wp2 = (ushort*)d_ws;                       // 384 KB reg-frag pack
        ushort* xT  = (ushort*)((char*)d_ws + xt_off);     // 32 MB
        transpose_prepack<<<dim3(TDIM / 64, CIN / 64, NB), dim3(256), 0, stream>>>(
            x, xT, w, (__hip_bfloat16*)wp2);
        deform_mfma_xt<<<dim3(1024), dim3(512), 0, stream>>>(xT, off, wp2, bias, out);
    } else {
        __hip_bfloat16* wp = (__hip_bfloat16*)d_ws;        // 384 KB LDS-image pack
        prepack_w<<<dim3(768), dim3(256), 0, stream>>>(w, wp);
        deform_mfma_gather<<<dim3(512), dim3(512), 0, stream>>>(x, off, wp, bias, out);
    }
}

// Round 24
// 62.986 us; speedup vs baseline: 5.4057x; 5.4057x over previous
//
#include <hip/hip_runtime.h>
#include <hip/hip_bf16.h>

typedef __attribute__((ext_vector_type(8))) short bf16x8;
typedef __attribute__((ext_vector_type(4))) float f32x4;

constexpr int NB = 16, CIN = 256, COUT = 256, TDIM = 4096, KS = 3, PADV = 1;
constexpr int TT = 64;             // t per block
constexpr int NSTEP = 12;          // 4 c-blocks x 3 taps

typedef __attribute__((address_space(1))) const unsigned int gu32;
typedef __attribute__((address_space(3))) unsigned int lu32;

static __device__ __forceinline__ ushort f2bf(float f) {
    union { __hip_bfloat16 h; ushort u; } cv;
    cv.h = __float2bfloat16(f);
    return cv.u;
}

// interp: r[i] = bf16( wa * a0[i] + wb * a1[i] )  — R19-measured dot2 form.
static __device__ __forceinline__ bf16x8 interp8(bf16x8 a0, bf16x8 a1,
                                                 unsigned int wpk, float wa, float wb) {
    union { bf16x8 v; unsigned int u[4]; } A0, A1;
    A0.v = a0; A1.v = a1;
    bf16x8 r;
#if __has_builtin(__builtin_amdgcn_fdot2_f32_bf16) && __has_builtin(__builtin_amdgcn_perm)
    typedef __attribute__((ext_vector_type(2))) __bf16 bf16x2v;
    bf16x2v w2 = __builtin_bit_cast(bf16x2v, wpk);
    #pragma unroll
    for (int j = 0; j < 4; ++j) {
        unsigned int pe = __builtin_amdgcn_perm(A1.u[j], A0.u[j], 0x05040100u); // elem 2j
        unsigned int po = __builtin_amdgcn_perm(A1.u[j], A0.u[j], 0x07060302u); // elem 2j+1
        float ve = __builtin_amdgcn_fdot2_f32_bf16(__builtin_bit_cast(bf16x2v, pe), w2, 0.0f, false);
        float vo = __builtin_amdgcn_fdot2_f32_bf16(__builtin_bit_cast(bf16x2v, po), w2, 0.0f, false);
        r[2 * j]     = (short)f2bf(ve);
        r[2 * j + 1] = (short)f2bf(vo);
    }
#else
    #pragma unroll
    for (int j = 0; j < 4; ++j) {
        float a0l = __uint_as_float(A0.u[j] << 16);
        float a0h = __uint_as_float(A0.u[j] & 0xffff0000u);
        float a1l = __uint_as_float(A1.u[j] << 16);
        float a1h = __uint_as_float(A1.u[j] & 0xffff0000u);
        r[2 * j]     = (short)f2bf(a0l * wa + a1l * wb);
        r[2 * j + 1] = (short)f2bf(a0h * wa + a1h * wb);
    }
#endif
    return r;
}

// x (B,C,T) f32 -> xT (B,T,C) bf16 (64c x 64t LDS tile), PLUS fused prepack of
// wp2 (reg-frag W pack): 4096 blocks x 48 items = 196608.
// wp2 slot = (((s*2+ot)*4+wid)*2+kb)*2+mf, 1 KB each; o = ot*128+wid*32+mf*16+
// (lane&15), c = (s/3)*64 + kb*32 + (lane>>4)*8 + e, k = s%3.
__global__ __launch_bounds__(256) void transpose_prepack(
    const float* __restrict__ x, ushort* __restrict__ xT,
    const float* __restrict__ w, __hip_bfloat16* __restrict__ wp2) {
    __shared__ ushort tile[64][72];
    const int b  = blockIdx.z;
    const int c0 = blockIdx.y * 64;
    const int t0 = blockIdx.x * 64;
    const int tid = threadIdx.x;
    // fused prepack: 48 items per block
    {
        int gid = ((blockIdx.z * gridDim.y + blockIdx.y) * gridDim.x + blockIdx.x);
        if (tid < 48) {
            int idx = gid * 48 + tid;                  // < 196608
            int e    = idx & 7;
            int lane = (idx >> 3) & 63;
            int mf   = (idx >> 9) & 1;
            int kb   = (idx >> 10) & 1;
            int wid  = (idx >> 11) & 3;
            int ot   = (idx >> 13) & 1;
            int s    = idx >> 14;                      // 0..11
            int o = ot * 128 + wid * 32 + mf * 16 + (lane & 15);
            int k = s % 3;
            int c = (s / 3) * 64 + kb * 32 + (lane >> 4) * 8 + e;
            wp2[idx] = __float2bfloat16(w[(o * CIN + c) * KS + k]);
        }
    }
    {
        const int c  = tid >> 2;
        const int tq = (tid & 3) << 4;
        const float* src = x + ((size_t)(b * CIN + c0 + c)) * TDIM + t0 + tq;
        #pragma unroll
        for (int i = 0; i < 4; ++i) {
            float4 f = *(const float4*)(src + 4 * i);
            tile[tq + 4 * i + 0][c] = f2bf(f.x);
            tile[tq + 4 * i + 1][c] = f2bf(f.y);
            tile[tq + 4 * i + 2][c] = f2bf(f.z);
            tile[tq + 4 * i + 3][c] = f2bf(f.w);
        }
    }
    __syncthreads();
    {
        const int t = tid >> 2;
        const int q = tid & 3;
        const uint4* lp = (const uint4*)&tile[t][q * 16];
        uint4 v0 = lp[0], v1 = lp[1];
        uint4* dst = (uint4*)(xT + ((size_t)b * TDIM + t0 + t) * CIN + c0 + q * 16);
        dst[0] = v0;
        dst[1] = v1;
    }
}

// legacy pack for the fallback kernel (LDS image, pre-swizzled)
__global__ __launch_bounds__(256) void prepack_w(const float* __restrict__ w,
                                                 __hip_bfloat16* __restrict__ wp) {
    int idx = blockIdx.x * 256 + threadIdx.x;
    if (idx >= NSTEP * COUT * 64) return;
    int e  = idx & 7;
    int j  = (idx >> 3) & 7;
    int o  = (idx >> 6) & (COUT - 1);
    int s  = idx >> 14;
    int k  = s % 3;
    int c  = (s / 3) * 64 + ((j ^ (o & 7)) << 3) + e;
    wp[idx] = __float2bfloat16(w[(o * CIN + c) * KS + k]);
}

// ---- main kernel: 512 threads, 256o x 64t tile, shared V, 128-VGPR budget ----
__global__ __launch_bounds__(512, 4) void deform_mfma_xt(
    const ushort* __restrict__ xT,            // (NB, TDIM, CIN) bf16
    const float* __restrict__ off,            // (NB, 2*KS, TDIM, 1)
    const ushort* __restrict__ wp2,           // reg-frag pack, 384 KB
    const float* __restrict__ bias,           // (COUT)
    float* __restrict__ out)                  // (NB, COUT, TDIM)
{
    __shared__ ushort v_s[TT * 64];         // 8 KB swizzled V tile [t][c]
    __shared__ int4   sP[KS][TT];           // {base*CIN, wpk, waf32, wbf32}

    const int tid = threadIdx.x;

    // XCD swizzle: 1024 blocks; XCD q (= bid&7) owns batches {2q, 2q+1}.
    const int bid = blockIdx.x;            // 0..1023
    const int q   = bid & 7;
    const int r   = bid >> 3;              // 0..127
    const int b   = 2 * q + (r >> 6);
    const int tt0 = (r & 63) * TT;

    // ---- Phase A: per-(k,t) base row + pair-ordered weights ----
    if (tid < KS * TT) {
        int k = tid >> 6, j = tid & (TT - 1);
        int t = tt0 + j;
        float dyr = off[((b * 2 * KS + 2 * k) * TDIM) + t];
        float dxr = off[((b * 2 * KS + 2 * k + 1) * TDIM) + t];
        float dyk = dyr - (float)(k - PADV);
        float py  = (float)(t - PADV + k) + dyk;
        float i0f = floorf(py);
        float fr  = py - i0f;
        int i0 = (int)i0f, i1 = i0 + 1;
        float wx = fmaxf(0.0f, 1.0f - fabsf(dxr));
        float w0 = (1.0f - fr) * wx * ((i0 >= 0 && i0 < TDIM) ? 1.0f : 0.0f);
        float w1 = fr * wx * ((i1 >= 0 && i1 < TDIM) ? 1.0f : 0.0f);
        int base = min(max(i0, 0), TDIM - 2);
        bool iA = (i0 == base);
        float wa = iA ? w0 : ((i0 + 1 == base) ? w1 : 0.0f);
        float wb = iA ? w1 : ((i0 == base + 1) ? w0 : 0.0f);
        int4 p;
        p.x = base * CIN;                  // pre-scaled row offset (elements)
        p.y = (int)((unsigned)f2bf(wa) | ((unsigned)f2bf(wb) << 16));
        p.z = __float_as_int(wa);
        p.w = __float_as_int(wb);
        sP[k][j] = p;
    }

    const int wid  = tid >> 6;             // 0..7 -> o sub-tile (wid*32)
    const int lane = tid & 63;
    const int lr   = lane & 15;
    const int lg   = lane >> 4;
    const int ot   = wid >> 2;             // wp2 pack dims
    const int wid3 = wid & 3;

    // V-phase mapping: 8 lanes per t, 64 t-rows over 512 threads (1 row/thread)
    const int tg   = tid >> 3;             // 0..63
    const int slot = tid & 7;
    const int voffA = (tg * 128 + slot * 16) ^ ((tg & 7) << 4);

    f32x4 acc[2][4];
    #pragma unroll
    for (int i = 0; i < 2; ++i)
        #pragma unroll
        for (int j = 0; j < 4; ++j) acc[i][j] = (f32x4)0.0f;

    const ushort* xTb = xT + (size_t)b * TDIM * CIN;

    __syncthreads();   // sP visible to all

    // ---- Prologue: W(0) frags + gather(0) + interp -> pk ----
    bf16x8 af0, af1, af2, af3;
    bf16x8 pk0;
    {
        const ushort* wslot = wp2 + (size_t)(((0 * 2 + ot) * 4 + wid3) * 4) * 512 + lane * 8;
        af0 = *(const bf16x8*)(wslot);
        af1 = *(const bf16x8*)(wslot + 512);
        af2 = *(const bf16x8*)(wslot + 1024);
        af3 = *(const bf16x8*)(wslot + 1536);
        int4 e0 = sP[0][tg];
        const ushort* rowA = xTb + e0.x + slot * 8;
        bf16x8 a0 = *(const bf16x8*)rowA;
        bf16x8 a1 = *(const bf16x8*)(rowA + CIN);
        pk0 = interp8(a0, a1, (unsigned)e0.y, __int_as_float(e0.z), __int_as_float(e0.w));
    }

    #pragma unroll 1
    for (int s = 0; s < NSTEP; ++s) {
        const int sn  = (s + 1 < NSTEP) ? s + 1 : NSTEP - 1;   // clamped prefetch
        const int kn  = sn % 3;
        const int cbn = (sn / 3) * 64;

        __builtin_amdgcn_s_barrier();          // B1: v_s writable (MFMA(s-1) done)
        __builtin_amdgcn_sched_barrier(0);

        // commit V(s) from regs
        *(bf16x8*)((char*)v_s + voffA) = pk0;

        // prefetch W(s+1) frags -> an*
        const ushort* wslot = wp2 + (size_t)(((sn * 2 + ot) * 4 + wid3) * 4) * 512 + lane * 8;
        bf16x8 an0 = *(const bf16x8*)(wslot);
        bf16x8 an1 = *(const bf16x8*)(wslot + 512);
        bf16x8 an2 = *(const bf16x8*)(wslot + 1024);
        bf16x8 an3 = *(const bf16x8*)(wslot + 1536);

        // prefetch gather(s+1) -> ga* (stays in flight through MFMA)
        int4 e0 = sP[kn][tg];
        const ushort* rowA = xTb + e0.x + cbn + slot * 8;
        bf16x8 ga0 = *(const bf16x8*)rowA;
        bf16x8 ga1 = *(const bf16x8*)(rowA + CIN);

        __builtin_amdgcn_sched_barrier(0);
        // own ds_write (and sP reads) complete; vmcnt NOT drained
        asm volatile("s_waitcnt lgkmcnt(0)" ::: "memory");
        __builtin_amdgcn_sched_barrier(0);
        __builtin_amdgcn_s_barrier();          // B2: v_s ready for all waves
        __builtin_amdgcn_sched_barrier(0);

        // ---- MFMA(s): wave computes 32(o) x 64(t), K=64; af already in regs ----
        #pragma unroll
        for (int kb = 0; kb < 2; ++kb) {
            const int kk = kb * 32 + lg * 8;
            bf16x8 bfr[4];
            #pragma unroll
            for (int nf = 0; nf < 4; ++nf) {
                int tc = nf * 16 + lr;
                int byte = (tc * 128 + kk * 2) ^ ((tc & 7) << 4);
                bfr[nf] = *(const bf16x8*)((const char*)v_s + byte);
            }
            bf16x8 a0 = kb ? af2 : af0;
            bf16x8 a1 = kb ? af3 : af1;
            #pragma unroll
            for (int nf = 0; nf < 4; ++nf) {
                acc[0][nf] = __builtin_amdgcn_mfma_f32_16x16x32_bf16(a0, bfr[nf], acc[0][nf], 0, 0, 0);
                acc[1][nf] = __builtin_amdgcn_mfma_f32_16x16x32_bf16(a1, bfr[nf], acc[1][nf], 0, 0, 0);
            }
        }
        __builtin_amdgcn_sched_barrier(0);

        // ---- interp(s+1): compiler inserts vmcnt waits for ga* here ----
        pk0 = interp8(ga0, ga1, (unsigned)e0.y, __int_as_float(e0.z), __int_as_float(e0.w));
        af0 = an0; af1 = an1; af2 = an2; af3 = an3;
    }

    // ---- Epilogue: D col = lane&15 (t), row = (lane>>4)*4 + reg (o) ----
    #pragma unroll
    for (int mf = 0; mf < 2; ++mf) {
        #pragma unroll
        for (int rg = 0; rg < 4; ++rg) {
            int o = wid * 32 + mf * 16 + lg * 4 + rg;
            float bv = bias[o];
            float* orow = out + (size_t)(b * COUT + o) * TDIM + tt0;
            #pragma unroll
            for (int nf = 0; nf < 4; ++nf)
                __builtin_nontemporal_store(acc[mf][nf][rg] + bv, &orow[nf * 16 + lr]);
        }
    }
}

// ---- fallback (proven R6 kernel, 128-t tile): scalar gathers from x ----
__global__ __launch_bounds__(512, 4) void deform_mfma_gather(
    const float* __restrict__ x,
    const float* __restrict__ off,
    const __hip_bfloat16* __restrict__ wp,
    const float* __restrict__ bias,
    float* __restrict__ out)
{
    __shared__ ushort w_s[COUT * 64];
    __shared__ ushort v_s[128 * 64];
    __shared__ int4   sP[KS][128];

    const int tid = threadIdx.x;
    const int bid  = blockIdx.x;
    const int q    = bid & 7;
    const int r    = bid >> 3;
    const int b    = 2 * q + (r >> 5);
    const int tt0  = (r & 31) * 128;

    if (tid < KS * 128) {
        int k = tid >> 7, j = tid & 127;
        int t = tt0 + j;
        float dyr = off[((b * 2 * KS + 2 * k) * TDIM) + t];
        float dxr = off[((b * 2 * KS + 2 * k + 1) * TDIM) + t];
        float py  = (float)(t - PADV + k) + dyr - (float)(k - PADV);
        float i0f = floorf(py);
        float fr  = py - i0f;
        int i0 = (int)i0f, i1 = i0 + 1;
        float wx = fmaxf(0.0f, 1.0f - fabsf(dxr));
        float w0 = (1.0f - fr) * wx * ((i0 >= 0 && i0 < TDIM) ? 1.0f : 0.0f);
        float w1 = fr * wx * ((i1 >= 0 && i1 < TDIM) ? 1.0f : 0.0f);
        int4 p;
        p.x = min(max(i0, 0), TDIM - 1);
        p.y = min(max(i1, 0), TDIM - 1);
        p.z = __float_as_int(w0);
        p.w = __float_as_int(w1);
        sP[k][j] = p;
    }

    const int wid    = tid >> 6;
    const int lane   = tid & 63;
    const int o_base = (wid >> 1) * 64;
    const int t_base = (wid & 1) * 64;
    const int lr     = lane & 15;
    const int lg     = lane >> 4;

    f32x4 acc[4][4];
    #pragma unroll
    for (int i = 0; i < 4; ++i)
        #pragma unroll
        for (int j = 0; j < 4; ++j) acc[i][j] = (f32x4)0.0f;

    const float* xb = x + (size_t)b * CIN * TDIM;

    for (int cb = 0; cb < 4; ++cb) {
      for (int k = 0; k < 3; ++k) {
        const int s_idx = cb * 3 + k;
        const int c0    = cb * 64;
        __syncthreads();
        {
            const char* gbase = (const char*)wp + (size_t)s_idx * 32768 + wid * 4096 + lane * 16;
            char* lbase = (char*)w_s + wid * 4096;
            #pragma unroll
            for (int i = 0; i < 4; ++i)
                __builtin_amdgcn_global_load_lds((gu32*)(gbase + i * 1024),
                                                 (lu32*)(lbase + i * 1024), 16, 0, 0);
        }
        {
            const int coct0 = tid >> 7;
            const int t     = tid & 127;
            int4 p = sP[k][t];
            const float* xr0 = xb + (size_t)(c0 + coct0 * 8) * TDIM;
            const float* xr1 = xr0 + (size_t)32 * TDIM;
            float g0[16], g1[16];
            #pragma unroll
            for (int i = 0; i < 8; ++i) {
                g0[2 * i]     = xr0[p.x];
                g0[2 * i + 1] = xr0[p.y];
                xr0 += TDIM;
            }
            #pragma unroll
            for (int i = 0; i < 8; ++i) {
                g1[2 * i]     = xr1[p.x];
                g1[2 * i + 1] = xr1[p.y];
                xr1 += TDIM;
            }
            float w0 = __int_as_float(p.z), w1 = __int_as_float(p.w);
            bf16x8 pk0, pk1;
            #pragma unroll
            for (int i = 0; i < 8; ++i) {
                pk0[i] = (short)f2bf(g0[2 * i] * w0 + g0[2 * i + 1] * w1);
                pk1[i] = (short)f2bf(g1[2 * i] * w0 + g1[2 * i + 1] * w1);
            }
            int row = t * 128;
            int swz = (t & 7) << 4;
            *(bf16x8*)((char*)v_s + ((row + coct0 * 16) ^ swz))       = pk0;
            *(bf16x8*)((char*)v_s + ((row + (coct0 + 4) * 16) ^ swz)) = pk1;
        }
        __syncthreads();
        #pragma unroll
        for (int kb = 0; kb < 2; ++kb) {
            const int kk = kb * 32 + lg * 8;
            bf16x8 bfr[4];
            #pragma unroll
            for (int nf = 0; nf < 4; ++nf) {
                int tc = t_base + nf * 16 + lr;
                int byte = (tc * 128 + kk * 2) ^ ((tc & 7) << 4);
                bfr[nf] = *(const bf16x8*)((const char*)v_s + byte);
            }
            #pragma unroll
            for (int mf = 0; mf < 4; ++mf) {
                int o  = o_base + mf * 16 + lr;
                int byte = (o * 128 + kk * 2) ^ ((o & 7) << 4);
                bf16x8 af = *(const bf16x8*)((const char*)w_s + byte);
                #pragma unroll
                for (int nf = 0; nf < 4; ++nf)
                    acc[mf][nf] = __builtin_amdgcn_mfma_f32_16x16x32_bf16(
                        af, bfr[nf], acc[mf][nf], 0, 0, 0);
            }
        }
      }
    }

    #pragma unroll
    for (int mf = 0; mf < 4; ++mf) {
        #pragma unroll
        for (int rg = 0; rg < 4; ++rg) {
            int o = o_base + mf * 16 + lg * 4 + rg;
            float bv = bias[o];
            float* orow = out + (size_t)(b * COUT + o) * TDIM + tt0 + t_base;
            #pragma unroll
            for (int nf = 0; nf < 4; ++nf)
                orow[nf * 16 + lr] = acc[mf][nf][rg] + bv;
        }
    }
}

extern "C" void kernel_launch(void* const* d_in, const int* in_sizes, int n_in,
                              void* d_out, int out_size, void* d_ws, size_t ws_size,
                              hipStream_t stream) {
    const float* x    = (const float*)d_in[0];
    const float* off  = (const float*)d_in[1];
    const float* w    = (const float*)d_in[2];
    const float* bias = (const float*)d_in[3];
    float* out = (float*)d_out;

    const size_t xt_off  = 512 * 1024;
    const size_t xt_need = xt_off + (size_t)NB * TDIM * CIN * sizeof(ushort);

    if (ws_size >= xt_need) {
        ushort* wp2 = (ushort*)d_ws;                       // 384 KB reg-frag pack
        ushort* xT  = (ushort*)((char*)d_ws + xt_off);     // 32 MB
        transpose_prepack<<<dim3(TDIM / 64, CIN / 64, NB), dim3(256), 0, stream>>>(
            x, xT, w, (__hip_bfloat16*)wp2);
        deform_mfma_xt<<<dim3(1024), dim3(512), 0, stream>>>(xT, off, wp2, bias, out);
    } else {
        __hip_bfloat16* wp = (__hip_bfloat16*)d_ws;        // 384 KB LDS-image pack
        prepack_w<<<dim3(768), dim3(256), 0, stream>>>(w, wp);
        deform_mfma_gather<<<dim3(512), dim3(512), 0, stream>>>(x, off, wp, bias, out);
    }
}